// Round 19
// baseline (81.184 us; speedup 1.0000x reference)
//
#include <hip/hip_runtime.h>
#include <math.h>

#define C_ 8
#define B_ 4
#define T_ 4096
#define D_ 128
#define TT 64
#define NCH (T_ / TT)                       // 64 chunks
#define CBTD ((size_t)C_ * B_ * T_ * D_)    // 16777216
#define SSIZE ((size_t)2 * C_ * B_ * NCH * D_)  // 524288 floats

typedef __attribute__((ext_vector_type(8))) short short8;
typedef __attribute__((ext_vector_type(4))) float f32x4;
typedef __attribute__((ext_vector_type(8))) unsigned short u16x8;
typedef __attribute__((ext_vector_type(4))) unsigned short u16x4;

__device__ __forceinline__ float lam_of(int c) {
  return (float)(1.0 - exp2(-(double)c * (13.0 / 7.0)));
}

__device__ __forceinline__ float decay_pow(float lam, float l2lam, int n) {
  if (n == 0) return 1.0f;
  if (lam == 0.0f) return 0.0f;
  return exp2f((float)n * l2lam);
}

__device__ __forceinline__ unsigned short f2bf(float x) {
  unsigned u = __float_as_uint(x);
  unsigned r = (u + 0x7FFFu + ((u >> 16) & 1u)) >> 16;   // RNE
  return (unsigned short)r;
}

// ---- pre-kernel: W -> bf16 in MFMA FRAGMENT ORDER (r13, confirmed)
__global__ __launch_bounds__(256)
void wcvt_kernel(const float* __restrict__ Wf, const float* __restrict__ Wb,
                 unsigned short* __restrict__ Wt) {
  __shared__ unsigned short Tq[128][130];   // Tq[e][d]
  const int blk = blockIdx.x;          // dir*8 + c
  const float* src = ((blk & 8) ? Wb : Wf) + (size_t)(blk & 7) * D_ * D_;
  const int tid = threadIdx.x;
  for (int i = 0; i < 16; ++i) {
    int fidx = tid + 256 * i;
    int d = fidx >> 5, e4 = (fidx & 31) * 4;
    float4 v = *(const float4*)(src + (size_t)d * D_ + e4);
    Tq[e4 + 0][d] = f2bf(v.x);
    Tq[e4 + 1][d] = f2bf(v.y);
    Tq[e4 + 2][d] = f2bf(v.z);
    Tq[e4 + 3][d] = f2bf(v.w);
  }
  __syncthreads();
  short8* dst = (short8*)(Wt + (size_t)blk * D_ * D_);
  for (int i = 0; i < 8; ++i) {
    int o = tid + 256 * i;
    int f = o >> 8, ks = (o >> 6) & 3, l4s = (o >> 4) & 3, l15s = o & 15;
    short8 t;
    #pragma unroll
    for (int j = 0; j < 8; ++j)
      t[j] = (short)Tq[f * 16 + l15s][ks * 32 + l4s * 8 + j];
    dst[o] = t;
  }
}

// ---- Phase A: dir-merged MFMA gate + local scan; bf16 LDS staging (34 KB total)
//      c==0: reconstruct f32 from bf16 and store final. c>0: store packed bf16.
__global__ __launch_bounds__(256)
void gate_mfma_kernel(const float* __restrict__ z,
                      const unsigned short* __restrict__ Wt,
                      const float* __restrict__ bf, const float* __restrict__ bb,
                      float* __restrict__ out, float* __restrict__ S) {
  __shared__ float term[2][16][132];     // both dirs' group terminals (16.9 KB)
  __shared__ unsigned short sb16[64][136];  // bf16 store-staging (17.4 KB)

  const int bi = blockIdx.x;
  const int tile = bi & (NCH - 1);
  const int b = (bi >> 6) & (B_ - 1);
  const int c = bi >> 8;
  const int tid = threadIdx.x;
  const int lane = tid & 63;
  const int w = tid >> 6;
  const int l15 = lane & 15;
  const int l4 = lane >> 4;

  const float lam = lam_of(c);
  float lp[5];
  lp[0] = 1.f;
  #pragma unroll
  for (int i = 1; i < 5; ++i) lp[i] = lp[i - 1] * lam;

  const float* zsrc = z + ((size_t)(c * B_ + b) * T_ + tile * TT) * D_;

  // A-fragments direct from global
  short8 afrag[4];
  const int rowA = w * 16 + l15;
  #pragma unroll
  for (int ks = 0; ks < 4; ++ks) {
    const float* p = zsrc + (size_t)rowA * D_ + ks * 32 + l4 * 8;
    float4 a0 = *(const float4*)p;
    float4 a1 = *(const float4*)(p + 4);
    short8 t;
    t[0] = (short)f2bf(a0.x); t[1] = (short)f2bf(a0.y);
    t[2] = (short)f2bf(a0.z); t[3] = (short)f2bf(a0.w);
    t[4] = (short)f2bf(a1.x); t[5] = (short)f2bf(a1.y);
    t[6] = (short)f2bf(a1.z); t[7] = (short)f2bf(a1.w);
    afrag[ks] = t;
  }

  // epilogue z in C-fragment layout (L1-hot)
  float zreg[8][4];
  const int rowE = w * 16 + l4 * 4;
  #pragma unroll
  for (int f = 0; f < 8; ++f)
    #pragma unroll
    for (int r = 0; r < 4; ++r)
      zreg[f][r] = zsrc[(size_t)(rowE + r) * D_ + f * 16 + l15];

  // both dirs' GEMMs in one dependence window (fragment-linear B loads)
  const short8* wf0 = (const short8*)(Wt + (size_t)(0 * 8 + c) * D_ * D_);
  const short8* wf1 = (const short8*)(Wt + (size_t)(1 * 8 + c) * D_ * D_);

  f32x4 acc[2][8];
  #pragma unroll
  for (int d = 0; d < 2; ++d)
    #pragma unroll
    for (int f = 0; f < 8; ++f) acc[d][f] = (f32x4){0.f, 0.f, 0.f, 0.f};

  #pragma unroll
  for (int f = 0; f < 8; ++f) {
    #pragma unroll
    for (int ks = 0; ks < 4; ++ks) {
      short8 b0 = wf0[(f * 4 + ks) * 64 + lane];
      short8 b1 = wf1[(f * 4 + ks) * 64 + lane];
      acc[0][f] = __builtin_amdgcn_mfma_f32_16x16x32_bf16(afrag[ks], b0, acc[0][f], 0, 0, 0);
      acc[1][f] = __builtin_amdgcn_mfma_f32_16x16x32_bf16(afrag[ks], b1, acc[1][f], 0, 0, 0);
    }
  }

  // epilogues: v = sigmoid(logit)*z, 4-step register scan (in-place on acc)
  #pragma unroll
  for (int d = 0; d < 2; ++d) {
    const float* bias = (d ? bb : bf) + (size_t)c * D_;
    #pragma unroll
    for (int f = 0; f < 8; ++f) {
      const float bcol = bias[f * 16 + l15];
      float vv[4];
      #pragma unroll
      for (int r = 0; r < 4; ++r) {
        const float logit = acc[d][f][r] + bcol;
        const float g = 1.0f / (1.0f + __expf(-logit));
        vv[r] = g * zreg[f][r];
      }
      if (d == 0) {
        float h = 0.f;
        #pragma unroll
        for (int r = 0; r < 4; ++r) { h = fmaf(lam, h, vv[r]); acc[d][f][r] = h; }
      } else {
        float h = 0.f;
        #pragma unroll
        for (int r = 3; r >= 0; --r) { h = fmaf(lam, h, vv[r]); acc[d][f][r] = h; }
      }
      term[d][w * 4 + l4][f * 16 + l15] = (d == 0) ? acc[d][f][3] : acc[d][f][0];
    }
  }
  __syncthreads();

  // dual prefix: waves 0-1 dir0, waves 2-3 dir1
  {
    const int d = tid >> 7;
    const int col = tid & 127;
    float tg[16];
    #pragma unroll
    for (int g = 0; g < 16; ++g) tg[g] = term[d][g][col];
    float p = 0.f;
    const float l4p = lp[4];
    if (d == 0) {
      #pragma unroll
      for (int g = 0; g < 16; ++g) { float t = tg[g]; term[d][g][col] = p; p = fmaf(l4p, p, t); }
    } else {
      #pragma unroll
      for (int g = 15; g >= 0; --g) { float t = tg[g]; term[d][g][col] = p; p = fmaf(l4p, p, t); }
    }
    S[(((size_t)(d * C_ + c) * B_ + b) * NCH + tile) * D_ + col] = p;
  }

  // apply group carry -> bf16 staging, then store (f32 for c==0, packed bf16 for c>0)
  #pragma unroll
  for (int d = 0; d < 2; ++d) {
    __syncthreads();
    #pragma unroll
    for (int f = 0; f < 8; ++f) {
      const int col = f * 16 + l15;
      const float carry = term[d][w * 4 + l4][col];
      #pragma unroll
      for (int r = 0; r < 4; ++r) {
        const float dec = (d == 0) ? lp[r + 1] : lp[4 - r];
        sb16[rowE + r][col] = f2bf(fmaf(dec, carry, acc[d][f][r]));
      }
    }
    __syncthreads();
    float* dst = out + (size_t)d * CBTD +
                 ((size_t)(c * B_ + b) * T_ + tile * TT) * D_;
    if (c == 0) {
      // final output: expand bf16 -> f32, coalesced NT stores
      #pragma unroll
      for (int i = 0; i < 8; ++i) {
        int fidx = tid + 256 * i;
        int row = fidx >> 5, col4 = (fidx & 31) * 4;
        u16x4 hv = *(const u16x4*)&sb16[row][col4];
        f32x4 v;
        v.x = __uint_as_float((unsigned)hv[0] << 16);
        v.y = __uint_as_float((unsigned)hv[1] << 16);
        v.z = __uint_as_float((unsigned)hv[2] << 16);
        v.w = __uint_as_float((unsigned)hv[3] << 16);
        __builtin_nontemporal_store(v, (f32x4*)(dst + (size_t)row * D_ + col4));
      }
    } else {
      // packed bf16 intermediate into first 16 KB of this chunk's region
      unsigned short* hb = (unsigned short*)dst;
      #pragma unroll
      for (int i = 0; i < 4; ++i) {
        int fidx = tid + 256 * i;                  // 1024 chunks of 8 bf16
        int row = fidx >> 4, c8 = (fidx & 15) * 8;
        u16x8 o = *(const u16x8*)&sb16[row][c8];
        __builtin_nontemporal_store(o, (u16x8*)(hb + row * 128 + c8));
      }
    }
  }
}

// ---- Phase B: carry prefix across chunks (tiny)
__global__ __launch_bounds__(128)
void prefix_kernel(const float* __restrict__ S, float* __restrict__ Cin) {
  const int bi = blockIdx.x;        // (dir, c, b)
  const int dir = bi >> 5;
  const int c = (bi >> 2) & 7;
  const int b = bi & 3;
  const int e = threadIdx.x;
  const float lam = lam_of(c);
  const float l2lam = (lam > 0.f) ? log2f(lam) : 0.f;
  const float lamL = decay_pow(lam, l2lam, TT);
  const size_t base = ((size_t)(dir * C_ + c) * B_ + b) * NCH * D_ + e;
  float cin = 0.f;
  if (dir == 0) {
    for (int k = 0; k < NCH; ++k) {
      Cin[base + (size_t)k * D_] = cin;
      cin = fmaf(lamL, cin, S[base + (size_t)k * D_]);
    }
  } else {
    for (int k = NCH - 1; k >= 0; --k) {
      Cin[base + (size_t)k * D_] = cin;
      cin = fmaf(lamL, cin, S[base + (size_t)k * D_]);
    }
  }
}

// ---- Phase C: read packed bf16 local_h, add decayed carry, write f32 (c=0 skipped)
__global__ __launch_bounds__(256)
void apply_kernel(float* __restrict__ out, const float* __restrict__ Cin) {
  const int bi = blockIdx.x;          // ((dir*C + c)*B + b)*NCH + k
  const int k = bi & (NCH - 1);
  const int b = (bi >> 6) & 3;
  const int c = (bi >> 8) & 7;
  const int dir = bi >> 11;
  if (c == 0) return;                 // gate already wrote final f32
  const float lam = lam_of(c);
  const float l2lam = log2f(lam);
  const int tid = threadIdx.x;
  const int col4 = (tid & 31) * 4;

  const f32x4 carry = *(const f32x4*)
      (Cin + (((size_t)(dir * C_ + c) * B_ + b) * NCH + k) * D_ + col4);
  float* base = out + (size_t)dir * CBTD +
                ((size_t)(c * B_ + b) * T_ + k * TT) * D_;
  const unsigned short* hb = (const unsigned short*)base;

  // read ALL bf16 before any f32 write (regions overlap across threads)
  u16x4 hv[8];
  #pragma unroll
  for (int i = 0; i < 8; ++i) {
    const int row = (tid >> 5) + i * 8;
    hv[i] = *(const u16x4*)(hb + row * 128 + col4);
  }
  __syncthreads();

  #pragma unroll
  for (int i = 0; i < 8; ++i) {
    const int row = (tid >> 5) + i * 8;
    const int dist = (dir == 0) ? (row + 1) : (TT - row);
    const float dec = exp2f(l2lam * (float)dist);
    f32x4 h;
    h.x = fmaf(dec, carry.x, __uint_as_float((unsigned)hv[i][0] << 16));
    h.y = fmaf(dec, carry.y, __uint_as_float((unsigned)hv[i][1] << 16));
    h.z = fmaf(dec, carry.z, __uint_as_float((unsigned)hv[i][2] << 16));
    h.w = fmaf(dec, carry.w, __uint_as_float((unsigned)hv[i][3] << 16));
    __builtin_nontemporal_store(h, (f32x4*)(base + (size_t)row * D_ + col4));
  }
}

extern "C" void kernel_launch(void* const* d_in, const int* in_sizes, int n_in,
                              void* d_out, int out_size, void* d_ws, size_t ws_size,
                              hipStream_t stream) {
  const float* z  = (const float*)d_in[0];
  const float* Wf = (const float*)d_in[1];
  const float* bf = (const float*)d_in[2];
  const float* Wb = (const float*)d_in[3];
  const float* bb = (const float*)d_in[4];
  float* out = (float*)d_out;
  float* S   = (float*)d_ws;                      // 2 MB
  float* Cin = S + SSIZE;                         // 2 MB
  unsigned short* Wt = (unsigned short*)(Cin + SSIZE);  // 512 KB bf16

  wcvt_kernel<<<dim3(16), dim3(256), 0, stream>>>(Wf, Wb, Wt);
  gate_mfma_kernel<<<dim3(C_ * B_ * NCH), dim3(256), 0, stream>>>(
      z, Wt, bf, bb, out, S);
  prefix_kernel<<<dim3(2 * C_ * B_), dim3(128), 0, stream>>>(S, Cin);
  apply_kernel<<<dim3(2 * C_ * B_ * NCH), dim3(256), 0, stream>>>(out, Cin);
}

// Round 20
// 79.135 us; speedup vs baseline: 1.0259x; 1.0259x over previous
//
#include <hip/hip_runtime.h>
#include <hip/hip_bf16.h>
#include <math.h>

#define C_ 8
#define B_ 4
#define T_ 4096
#define D_ 128
#define TT 64
#define NCH (T_ / TT)                       // 64 chunks
#define CBTD ((size_t)C_ * B_ * T_ * D_)    // 16777216
#define SSIZE ((size_t)2 * C_ * B_ * NCH * D_)  // 524288 floats
#define LOG2E 1.44269504088896f

typedef __attribute__((ext_vector_type(8))) short short8;
typedef __attribute__((ext_vector_type(4))) float f32x4;
typedef __attribute__((ext_vector_type(8))) unsigned short u16x8;
typedef __attribute__((ext_vector_type(4))) unsigned short u16x4;

__device__ __forceinline__ float lam_of(int c) {
  return (float)(1.0 - exp2(-(double)c * (13.0 / 7.0)));
}

__device__ __forceinline__ float decay_pow(float lam, float l2lam, int n) {
  if (n == 0) return 1.0f;
  if (lam == 0.0f) return 0.0f;
  return exp2f((float)n * l2lam);
}

// native RNE f32->bf16 (HW cvt, not hand-rolled bit math)
__device__ __forceinline__ unsigned short f2bf(float x) {
  __hip_bfloat16 h = __float2bfloat16(x);
  unsigned short u;
  __builtin_memcpy(&u, &h, 2);
  return u;
}

// ---- pre-kernel: W*log2e -> bf16 in MFMA FRAGMENT ORDER (r13 layout + log2e fold)
__global__ __launch_bounds__(256)
void wcvt_kernel(const float* __restrict__ Wf, const float* __restrict__ Wb,
                 unsigned short* __restrict__ Wt) {
  __shared__ unsigned short Tq[128][130];   // Tq[e][d]
  const int blk = blockIdx.x;          // dir*8 + c
  const float* src = ((blk & 8) ? Wb : Wf) + (size_t)(blk & 7) * D_ * D_;
  const int tid = threadIdx.x;
  for (int i = 0; i < 16; ++i) {
    int fidx = tid + 256 * i;
    int d = fidx >> 5, e4 = (fidx & 31) * 4;
    float4 v = *(const float4*)(src + (size_t)d * D_ + e4);
    Tq[e4 + 0][d] = f2bf(v.x * LOG2E);
    Tq[e4 + 1][d] = f2bf(v.y * LOG2E);
    Tq[e4 + 2][d] = f2bf(v.z * LOG2E);
    Tq[e4 + 3][d] = f2bf(v.w * LOG2E);
  }
  __syncthreads();
  short8* dst = (short8*)(Wt + (size_t)blk * D_ * D_);
  for (int i = 0; i < 8; ++i) {
    int o = tid + 256 * i;
    int f = o >> 8, ks = (o >> 6) & 3, l4s = (o >> 4) & 3, l15s = o & 15;
    short8 t;
    #pragma unroll
    for (int j = 0; j < 8; ++j)
      t[j] = (short)Tq[f * 16 + l15s][ks * 32 + l4s * 8 + j];
    dst[o] = t;
  }
}

// ---- Phase A: dir-merged MFMA gate + local scan; scaled-logit sigmoid (exp2+rcp)
__global__ __launch_bounds__(256)
void gate_mfma_kernel(const float* __restrict__ z,
                      const unsigned short* __restrict__ Wt,
                      const float* __restrict__ bf, const float* __restrict__ bb,
                      float* __restrict__ out, float* __restrict__ S) {
  __shared__ float term[2][16][132];       // both dirs' group terminals (16.9 KB)
  __shared__ unsigned short sb16[64][136]; // bf16 store-staging (17.4 KB)

  const int bi = blockIdx.x;
  const int tile = bi & (NCH - 1);
  const int b = (bi >> 6) & (B_ - 1);
  const int c = bi >> 8;
  const int tid = threadIdx.x;
  const int lane = tid & 63;
  const int w = tid >> 6;
  const int l15 = lane & 15;
  const int l4 = lane >> 4;

  const float lam = lam_of(c);
  float lp[5];
  lp[0] = 1.f;
  #pragma unroll
  for (int i = 1; i < 5; ++i) lp[i] = lp[i - 1] * lam;

  const float* zsrc = z + ((size_t)(c * B_ + b) * T_ + tile * TT) * D_;

  // A-fragments direct from global
  short8 afrag[4];
  const int rowA = w * 16 + l15;
  #pragma unroll
  for (int ks = 0; ks < 4; ++ks) {
    const float* p = zsrc + (size_t)rowA * D_ + ks * 32 + l4 * 8;
    float4 a0 = *(const float4*)p;
    float4 a1 = *(const float4*)(p + 4);
    short8 t;
    t[0] = (short)f2bf(a0.x); t[1] = (short)f2bf(a0.y);
    t[2] = (short)f2bf(a0.z); t[3] = (short)f2bf(a0.w);
    t[4] = (short)f2bf(a1.x); t[5] = (short)f2bf(a1.y);
    t[6] = (short)f2bf(a1.z); t[7] = (short)f2bf(a1.w);
    afrag[ks] = t;
  }

  // epilogue z in C-fragment layout (L1-hot)
  float zreg[8][4];
  const int rowE = w * 16 + l4 * 4;
  #pragma unroll
  for (int f = 0; f < 8; ++f)
    #pragma unroll
    for (int r = 0; r < 4; ++r)
      zreg[f][r] = zsrc[(size_t)(rowE + r) * D_ + f * 16 + l15];

  // both dirs' GEMMs in one dependence window (fragment-linear B loads)
  const short8* wf0 = (const short8*)(Wt + (size_t)(0 * 8 + c) * D_ * D_);
  const short8* wf1 = (const short8*)(Wt + (size_t)(1 * 8 + c) * D_ * D_);

  f32x4 acc[2][8];
  #pragma unroll
  for (int d = 0; d < 2; ++d)
    #pragma unroll
    for (int f = 0; f < 8; ++f) acc[d][f] = (f32x4){0.f, 0.f, 0.f, 0.f};

  #pragma unroll
  for (int f = 0; f < 8; ++f) {
    #pragma unroll
    for (int ks = 0; ks < 4; ++ks) {
      short8 b0 = wf0[(f * 4 + ks) * 64 + lane];
      short8 b1 = wf1[(f * 4 + ks) * 64 + lane];
      acc[0][f] = __builtin_amdgcn_mfma_f32_16x16x32_bf16(afrag[ks], b0, acc[0][f], 0, 0, 0);
      acc[1][f] = __builtin_amdgcn_mfma_f32_16x16x32_bf16(afrag[ks], b1, acc[1][f], 0, 0, 0);
    }
  }

  // epilogues: logit' = (z*W + b)*log2e already; g = rcp(1 + 2^-logit'); scan
  #pragma unroll
  for (int d = 0; d < 2; ++d) {
    const float* bias = (d ? bb : bf) + (size_t)c * D_;
    #pragma unroll
    for (int f = 0; f < 8; ++f) {
      const float bcol = bias[f * 16 + l15] * LOG2E;
      float vv[4];
      #pragma unroll
      for (int r = 0; r < 4; ++r) {
        const float logit = acc[d][f][r] + bcol;
        const float g = __builtin_amdgcn_rcpf(1.0f + exp2f(-logit));
        vv[r] = g * zreg[f][r];
      }
      if (d == 0) {
        float h = 0.f;
        #pragma unroll
        for (int r = 0; r < 4; ++r) { h = fmaf(lam, h, vv[r]); acc[d][f][r] = h; }
      } else {
        float h = 0.f;
        #pragma unroll
        for (int r = 3; r >= 0; --r) { h = fmaf(lam, h, vv[r]); acc[d][f][r] = h; }
      }
      term[d][w * 4 + l4][f * 16 + l15] = (d == 0) ? acc[d][f][3] : acc[d][f][0];
    }
  }
  __syncthreads();

  // dual prefix: waves 0-1 dir0, waves 2-3 dir1
  {
    const int d = tid >> 7;
    const int col = tid & 127;
    float tg[16];
    #pragma unroll
    for (int g = 0; g < 16; ++g) tg[g] = term[d][g][col];
    float p = 0.f;
    const float l4p = lp[4];
    if (d == 0) {
      #pragma unroll
      for (int g = 0; g < 16; ++g) { float t = tg[g]; term[d][g][col] = p; p = fmaf(l4p, p, t); }
    } else {
      #pragma unroll
      for (int g = 15; g >= 0; --g) { float t = tg[g]; term[d][g][col] = p; p = fmaf(l4p, p, t); }
    }
    S[(((size_t)(d * C_ + c) * B_ + b) * NCH + tile) * D_ + col] = p;
  }

  // apply group carry -> bf16 staging, then store (f32 for c==0, packed bf16 for c>0)
  #pragma unroll
  for (int d = 0; d < 2; ++d) {
    __syncthreads();
    #pragma unroll
    for (int f = 0; f < 8; ++f) {
      const int col = f * 16 + l15;
      const float carry = term[d][w * 4 + l4][col];
      #pragma unroll
      for (int r = 0; r < 4; ++r) {
        const float dec = (d == 0) ? lp[r + 1] : lp[4 - r];
        sb16[rowE + r][col] = f2bf(fmaf(dec, carry, acc[d][f][r]));
      }
    }
    __syncthreads();
    float* dst = out + (size_t)d * CBTD +
                 ((size_t)(c * B_ + b) * T_ + tile * TT) * D_;
    if (c == 0) {
      #pragma unroll
      for (int i = 0; i < 8; ++i) {
        int fidx = tid + 256 * i;
        int row = fidx >> 5, col4 = (fidx & 31) * 4;
        u16x4 hv = *(const u16x4*)&sb16[row][col4];
        f32x4 v;
        v.x = __uint_as_float((unsigned)hv[0] << 16);
        v.y = __uint_as_float((unsigned)hv[1] << 16);
        v.z = __uint_as_float((unsigned)hv[2] << 16);
        v.w = __uint_as_float((unsigned)hv[3] << 16);
        __builtin_nontemporal_store(v, (f32x4*)(dst + (size_t)row * D_ + col4));
      }
    } else {
      unsigned short* hb = (unsigned short*)dst;   // first 16 KB of chunk's region
      #pragma unroll
      for (int i = 0; i < 4; ++i) {
        int fidx = tid + 256 * i;
        int row = fidx >> 4, c8 = (fidx & 15) * 8;
        u16x8 o = *(const u16x8*)&sb16[row][c8];
        __builtin_nontemporal_store(o, (u16x8*)(hb + row * 128 + c8));
      }
    }
  }
}

// ---- Phase B: carry prefix across chunks (tiny)
__global__ __launch_bounds__(128)
void prefix_kernel(const float* __restrict__ S, float* __restrict__ Cin) {
  const int bi = blockIdx.x;        // (dir, c, b)
  const int dir = bi >> 5;
  const int c = (bi >> 2) & 7;
  const int b = bi & 3;
  const int e = threadIdx.x;
  const float lam = lam_of(c);
  const float l2lam = (lam > 0.f) ? log2f(lam) : 0.f;
  const float lamL = decay_pow(lam, l2lam, TT);
  const size_t base = ((size_t)(dir * C_ + c) * B_ + b) * NCH * D_ + e;
  float cin = 0.f;
  if (dir == 0) {
    for (int k = 0; k < NCH; ++k) {
      Cin[base + (size_t)k * D_] = cin;
      cin = fmaf(lamL, cin, S[base + (size_t)k * D_]);
    }
  } else {
    for (int k = NCH - 1; k >= 0; --k) {
      Cin[base + (size_t)k * D_] = cin;
      cin = fmaf(lamL, cin, S[base + (size_t)k * D_]);
    }
  }
}

// ---- Phase C: read packed bf16 local_h, add decayed carry, write f32 (c=0 skipped)
__global__ __launch_bounds__(256)
void apply_kernel(float* __restrict__ out, const float* __restrict__ Cin) {
  const int bi = blockIdx.x;          // ((dir*C + c)*B + b)*NCH + k
  const int k = bi & (NCH - 1);
  const int b = (bi >> 6) & 3;
  const int c = (bi >> 8) & 7;
  const int dir = bi >> 11;
  if (c == 0) return;                 // gate already wrote final f32
  const float lam = lam_of(c);
  const float l2lam = log2f(lam);
  const int tid = threadIdx.x;
  const int col4 = (tid & 31) * 4;

  const f32x4 carry = *(const f32x4*)
      (Cin + (((size_t)(dir * C_ + c) * B_ + b) * NCH + k) * D_ + col4);
  float* base = out + (size_t)dir * CBTD +
                ((size_t)(c * B_ + b) * T_ + k * TT) * D_;
  const unsigned short* hb = (const unsigned short*)base;

  // read ALL bf16 before any f32 write (regions overlap across threads)
  u16x4 hv[8];
  #pragma unroll
  for (int i = 0; i < 8; ++i) {
    const int row = (tid >> 5) + i * 8;
    hv[i] = *(const u16x4*)(hb + row * 128 + col4);
  }
  __syncthreads();

  #pragma unroll
  for (int i = 0; i < 8; ++i) {
    const int row = (tid >> 5) + i * 8;
    const int dist = (dir == 0) ? (row + 1) : (TT - row);
    const float dec = exp2f(l2lam * (float)dist);
    f32x4 h;
    h.x = fmaf(dec, carry.x, __uint_as_float((unsigned)hv[i][0] << 16));
    h.y = fmaf(dec, carry.y, __uint_as_float((unsigned)hv[i][1] << 16));
    h.z = fmaf(dec, carry.z, __uint_as_float((unsigned)hv[i][2] << 16));
    h.w = fmaf(dec, carry.w, __uint_as_float((unsigned)hv[i][3] << 16));
    __builtin_nontemporal_store(h, (f32x4*)(base + (size_t)row * D_ + col4));
  }
}

extern "C" void kernel_launch(void* const* d_in, const int* in_sizes, int n_in,
                              void* d_out, int out_size, void* d_ws, size_t ws_size,
                              hipStream_t stream) {
  const float* z  = (const float*)d_in[0];
  const float* Wf = (const float*)d_in[1];
  const float* bf = (const float*)d_in[2];
  const float* Wb = (const float*)d_in[3];
  const float* bb = (const float*)d_in[4];
  float* out = (float*)d_out;
  float* S   = (float*)d_ws;                      // 2 MB
  float* Cin = S + SSIZE;                         // 2 MB
  unsigned short* Wt = (unsigned short*)(Cin + SSIZE);  // 512 KB bf16

  wcvt_kernel<<<dim3(16), dim3(256), 0, stream>>>(Wf, Wb, Wt);
  gate_mfma_kernel<<<dim3(C_ * B_ * NCH), dim3(256), 0, stream>>>(
      z, Wt, bf, bb, out, S);
  prefix_kernel<<<dim3(2 * C_ * B_), dim3(128), 0, stream>>>(S, Cin);
  apply_kernel<<<dim3(2 * C_ * B_ * NCH), dim3(256), 0, stream>>>(out, Cin);
}